// Round 4
// baseline (501.564 us; speedup 1.0000x reference)
//
#include <hip/hip_runtime.h>
#include <cstdint>

typedef __bf16 bf16;
typedef __bf16 bf16x8 __attribute__((ext_vector_type(8)));
typedef __bf16 bf16x4 __attribute__((ext_vector_type(4)));
typedef float f32x4 __attribute__((ext_vector_type(4)));

#define DIMN 2048
#define SEQ  2048
#define NH   16
#define HD   128

// -------- async global->LDS 16B helper (m97 pattern) --------
__device__ __forceinline__ void gld_lds16(const bf16* g, bf16* l) {
    __builtin_amdgcn_global_load_lds(
        (const __attribute__((address_space(1))) void*)g,
        (__attribute__((address_space(3))) void*)l,
        16, 0, 0);
}

// -------- all fp32->bf16 casts in ONE launch --------
// grid.x = 8192 (x) + 4*4096 (weights) = 24576 blocks; exact fit, no bounds checks.
__global__ __launch_bounds__(256) void cast_all(
    const float* __restrict__ x,
    const float* __restrict__ wq, const float* __restrict__ wk,
    const float* __restrict__ wv, const float* __restrict__ wo,
    bf16* __restrict__ xb,
    bf16* __restrict__ wqb, bf16* __restrict__ wkb,
    bf16* __restrict__ wvb, bf16* __restrict__ wob)
{
    int id = blockIdx.x;
    const float* src; bf16* dst; int i;
    if (id < 8192) { src = x; dst = xb; i = id * 256 + threadIdx.x; }
    else {
        id -= 8192;
        int w = id >> 12; id &= 4095;
        src = (w == 0) ? wq : (w == 1) ? wk : (w == 2) ? wv : wo;
        dst = (w == 0) ? wqb : (w == 1) ? wkb : (w == 2) ? wvb : wob;
        i = id * 256 + threadIdx.x;
    }
    float4 v = ((const float4*)src)[i];
    bf16x4 o;
    o[0] = (bf16)v.x; o[1] = (bf16)v.y; o[2] = (bf16)v.z; o[3] = (bf16)v.w;
    ((bf16x4*)dst)[i] = o;
}

// -------- GEMM: C[m][n] = sum_k A[m][k]*B[n][k] + bias[n]
// 128x128 tile, BK=64 (32 MFMA/barrier). Seg-XOR swizzled LDS, conflict-free.
// ~800 TF = m97-structure plateau; left as-is.
template<int OUT_F32>
__global__ __launch_bounds__(256) void gemm_bt(
    const bf16* __restrict__ A,
    const bf16* __restrict__ Bw0, const bf16* __restrict__ Bw1, const bf16* __restrict__ Bw2,
    const float* __restrict__ bias0, const float* __restrict__ bias1, const float* __restrict__ bias2,
    void* __restrict__ C0, void* __restrict__ C1, void* __restrict__ C2)
{
    const int K = DIMN, N = DIMN;
    const bf16* Bw = Bw0; const float* bias = bias0; void* Cout = C0;
    if (blockIdx.z == 1) { Bw = Bw1; bias = bias1; Cout = C1; }
    if (blockIdx.z == 2) { Bw = Bw2; bias = bias2; Cout = C2; }

    __shared__ __attribute__((aligned(16))) bf16 As[128 * 64];
    __shared__ __attribute__((aligned(16))) bf16 Bs[128 * 64];

    const int t    = threadIdx.x;
    const int lane = t & 63, wave = t >> 6;
    const int l15  = lane & 15, quad = lane >> 4;
    const int wm   = (wave >> 1) * 64, wn = (wave & 1) * 64;
    const long bm  = (long)blockIdx.y * 128;
    const long bn  = (long)blockIdx.x * 128;

    const bf16* agp[4]; const bf16* bgp[4]; bf16* asd[4]; bf16* bsd[4];
#pragma unroll
    for (int it = 0; it < 4; it++) {
        int fs  = it * 256 + t;
        int row = fs >> 3;
        int gs  = (fs & 7) ^ (row & 7);
        agp[it] = A  + (bm + row) * (long)K + gs * 8;
        bgp[it] = Bw + (bn + row) * (long)K + gs * 8;
        asd[it] = As + fs * 8;
        bsd[it] = Bs + fs * 8;
    }
    const int swl = l15 & 7;

    f32x4 acc[4][4] = {};

    for (int k0 = 0; k0 < K; k0 += 64) {
#pragma unroll
        for (int it = 0; it < 4; it++) {
            gld_lds16(agp[it] + k0, asd[it]);
            gld_lds16(bgp[it] + k0, bsd[it]);
        }
        __syncthreads();

#pragma unroll
        for (int ks2 = 0; ks2 < 2; ks2++) {
            const int sw = ((ks2 * 4 + quad) ^ swl) * 8;
            bf16x8 af[4], bfr[4];
#pragma unroll
            for (int i = 0; i < 4; i++)
                af[i] = *(const bf16x8*)(As + (wm + i * 16 + l15) * 64 + sw);
#pragma unroll
            for (int j = 0; j < 4; j++)
                bfr[j] = *(const bf16x8*)(Bs + (wn + j * 16 + l15) * 64 + sw);
#pragma unroll
            for (int i = 0; i < 4; i++)
#pragma unroll
                for (int j = 0; j < 4; j++)
                    acc[i][j] = __builtin_amdgcn_mfma_f32_16x16x32_bf16(af[i], bfr[j], acc[i][j], 0, 0, 0);
        }
        __syncthreads();
    }

#pragma unroll
    for (int j = 0; j < 4; j++) {
        const long col = bn + wn + j * 16 + l15;
        const float bv = bias[col];
#pragma unroll
        for (int i = 0; i < 4; i++) {
            const long row0 = bm + wm + i * 16 + quad * 4;
#pragma unroll
            for (int r = 0; r < 4; r++) {
                float v = acc[i][j][r] + bv;
                if (OUT_F32) ((float*)Cout)[(row0 + r) * N + col] = v;
                else         ((bf16*)Cout)[(row0 + r) * N + col] = (bf16)v;
            }
        }
    }
}

// -------- fused (RMSNorm+RoPE on q,k) + (V transpose) in one launch --------
// grid.x: [0,8192) rmsnorm rows, [8192,10240) transpose tiles.
__global__ __launch_bounds__(256) void norm_prep(
    bf16* __restrict__ q, bf16* __restrict__ k,
    const float* __restrict__ gq, const float* __restrict__ gk,
    const float* __restrict__ freqs,
    const bf16* __restrict__ vin, bf16* __restrict__ vt)
{
    const int id = blockIdx.x;
    const int t = threadIdx.x;
    if (id < 8192) {
        const int qk  = id >> 12;
        const int row = id & 4095;                 // b*SEQ + s
        bf16* ptr = qk ? k : q;
        const float* g = qk ? gk : gq;
        const float osc = qk ? 1.0f : 0.08838834764831845f;   // fold 1/sqrt(HD) into Q
        const int s = row & (SEQ - 1);
        const int lane = t & 63, wave = t >> 6;

        bf16* base = ptr + (long)row * DIMN + t * 8;
        bf16x8 raw = *(const bf16x8*)base;
        float v[8]; float ss = 0.f;
#pragma unroll
        for (int j = 0; j < 8; j++) { v[j] = (float)raw[j]; ss += v[j] * v[j]; }
#pragma unroll
        for (int off = 32; off; off >>= 1) ss += __shfl_xor(ss, off, 64);
        __shared__ float red[4];
        if (lane == 0) red[wave] = ss;
        __syncthreads();
        float tot = red[0] + red[1] + red[2] + red[3];
        float rn = rsqrtf(tot * (1.0f / DIMN) + 1e-6f);

        const int e0 = t * 8;
        bf16x8 o;
#pragma unroll
        for (int pp = 0; pp < 4; pp++) {
            int e = e0 + pp * 2;
            float xr = v[pp * 2]     * rn * g[e];
            float xi = v[pp * 2 + 1] * rn * g[e + 1];
            int lc = (e >> 1) & 63;
            float cr = freqs[s * 128 + lc * 2];
            float ci = freqs[s * 128 + lc * 2 + 1];
            o[pp * 2]     = (bf16)((xr * cr - xi * ci) * osc);
            o[pp * 2 + 1] = (bf16)((xr * ci + xi * cr) * osc);
        }
        *(bf16x8*)base = o;
    } else {
        const int tid = id - 8192;
        const int b = tid >> 10, rem = tid & 1023;
        const int st = rem & 31, ct = rem >> 5;
        __shared__ float tile[64][65];
        const int tx = t & 63, ty = t >> 6;
#pragma unroll
        for (int ii = 0; ii < 16; ii++) {
            int r = ii * 4 + ty;
            tile[r][tx] = (float)vin[((long)(b * SEQ + st * 64 + r)) * DIMN + ct * 64 + tx];
        }
        __syncthreads();
#pragma unroll
        for (int ii = 0; ii < 16; ii++) {
            int c = ii * 4 + ty;
            vt[((long)(b * DIMN + ct * 64 + c)) * SEQ + st * 64 + tx] = (bf16)tile[tx][c];
        }
    }
}

// -------- flash-style attention v2: 2 waves x BM=64/wave (register reuse x2 vs v1).
// S^T form (A=K, B=Q): P stored b64; L-reduce deferred out of loop.
// Each K/V LDS fragment read now feeds 4 MFMAs. VGPR ~250, 2 waves/SIMD.
__global__ __launch_bounds__(128, 2) void attention(
    const bf16* __restrict__ Q, const bf16* __restrict__ Kb,
    const bf16* __restrict__ Vt, bf16* __restrict__ O)
{
    __shared__ __attribute__((aligned(16))) bf16 Ksh[64 * 128];    // [kr][d], seg^=(kr&15)
    __shared__ __attribute__((aligned(16))) bf16 Vsh[128 * 64];    // [d][kr], seg^=(d&7)
    __shared__ __attribute__((aligned(16))) bf16 Psh[2][64 * 72];  // per-wave P[m][kr]
    __shared__ float Lsh[2][64];

    const int t = threadIdx.x;
    const int lane = t & 63, w = t >> 6;
    const int l15 = lane & 15, quad = lane >> 4;
    const int bh = blockIdx.y, b = bh >> 4, h = bh & 15;
    const int qt = blockIdx.x;
    const long qrow0 = (long)b * SEQ + qt * 128 + w * 64;
    const bf16* qbase = Q  + qrow0 * DIMN + h * HD;
    const bf16* kbase = Kb + (long)b * SEQ * DIMN + h * HD;
    const bf16* vbase = Vt + (long)bh * HD * SEQ;

    // Q fragments resident (pre-scaled): B[m=l15][k=quad*8+j]
    bf16x8 qf[4][4];
#pragma unroll
    for (int im = 0; im < 4; im++)
#pragma unroll
        for (int kd = 0; kd < 4; kd++)
            qf[im][kd] = *(const bf16x8*)(qbase + (long)(im * 16 + l15) * DIMN + kd * 32 + quad * 8);

    // staging bases (XOR keys periodic in pass index -> 3 registers total)
    const int t4 = t >> 4;
    const int kseg0 = (t & 15) ^ t4;
    const long kb0 = (long)t4 * DIMN + kseg0 * 8;
    const long kb1 = (long)t4 * DIMN + (kseg0 ^ 8) * 8;
    const long vb0 = (long)(t >> 3) * SEQ + ((t & 7) ^ ((t >> 3) & 7)) * 8;

    f32x4 o_acc[4][8] = {};
    float Lt[4] = {0.f, 0.f, 0.f, 0.f};

    for (int kt = 0; kt < 32; kt++) {
        const bf16* kg = kbase + (long)(kt * 64) * DIMN;
        const bf16* vg = vbase + kt * 64;
#pragma unroll
        for (int it = 0; it < 8; it++) {
            gld_lds16(kg + (long)it * 8 * DIMN + ((it & 1) ? kb1 : kb0), Ksh + t * 8 + it * 1024);
            gld_lds16(vg + (long)it * 16 * SEQ + vb0, Vsh + t * 8 + it * 1024);
        }
        __syncthreads();

        // ---- S^T = K Q^T, processed in jk-pairs to bound register life ----
#pragma unroll
        for (int jp = 0; jp < 2; jp++) {
            f32x4 st[2][4] = {};
#pragma unroll
            for (int jj = 0; jj < 2; jj++) {
                const int jk = jp * 2 + jj;
#pragma unroll
                for (int kd = 0; kd < 4; kd++) {
                    bf16x8 kf = *(const bf16x8*)(Ksh + (jk * 16 + l15) * 128 + (((kd * 4 + quad) ^ l15) & 15) * 8);
#pragma unroll
                    for (int im = 0; im < 4; im++)
                        st[jj][im] = __builtin_amdgcn_mfma_f32_16x16x32_bf16(kf, qf[im][kd], st[jj][im], 0, 0, 0);
                }
            }
            // exp + P->LDS (b64) + per-lane partial L (reduce deferred to end)
#pragma unroll
            for (int jj = 0; jj < 2; jj++) {
                const int jk = jp * 2 + jj;
#pragma unroll
                for (int im = 0; im < 4; im++) {
                    bf16x4 pk;
                    float part = 0.f;
#pragma unroll
                    for (int r = 0; r < 4; r++) {
                        float e = __expf(st[jj][im][r]);
                        part += e;
                        pk[r] = (bf16)e;
                    }
                    *(bf16x4*)(Psh[w] + (im * 16 + l15) * 72 + jk * 16 + quad * 4) = pk;
                    Lt[im] += part;
                }
            }
        }
        // no barrier: Psh[w] wave-private, LDS in-order per wave

        // ---- O += P V ----
#pragma unroll
        for (int kd2 = 0; kd2 < 2; kd2++) {
            bf16x8 pa[4];
#pragma unroll
            for (int im = 0; im < 4; im++)
                pa[im] = *(const bf16x8*)(Psh[w] + (im * 16 + l15) * 72 + kd2 * 32 + quad * 8);
#pragma unroll
            for (int dj = 0; dj < 8; dj++) {
                bf16x8 vfr = *(const bf16x8*)(Vsh + (dj * 16 + l15) * 64 + (((kd2 * 4 + quad) ^ l15) & 7) * 8);
#pragma unroll
                for (int im = 0; im < 4; im++)
                    o_acc[im][dj] = __builtin_amdgcn_mfma_f32_16x16x32_bf16(pa[im], vfr, o_acc[im][dj], 0, 0, 0);
            }
        }
        __syncthreads();
    }

    // deferred L reduction over quads (butterfly -> all lanes hold total)
#pragma unroll
    for (int im = 0; im < 4; im++) {
        Lt[im] += __shfl_xor(Lt[im], 16, 64);
        Lt[im] += __shfl_xor(Lt[im], 32, 64);
    }
    if (quad == 0)
#pragma unroll
        for (int im = 0; im < 4; im++) Lsh[w][im * 16 + l15] = Lt[im];
    __syncthreads();

    // normalize + write (aliases Q buffer: block (qt,h) writes only rows/cols it alone read)
#pragma unroll
    for (int im = 0; im < 4; im++)
#pragma unroll
        for (int r = 0; r < 4; r++) {
            float inv = 1.0f / Lsh[w][im * 16 + quad * 4 + r];
            long orow = qrow0 + im * 16 + quad * 4 + r;
#pragma unroll
            for (int dj = 0; dj < 8; dj++)
                O[orow * DIMN + h * HD + dj * 16 + l15] = (bf16)(o_acc[im][dj][r] * inv);
        }
}

extern "C" void kernel_launch(void* const* d_in, const int* in_sizes, int n_in,
                              void* d_out, int out_size, void* d_ws, size_t ws_size,
                              hipStream_t stream) {
    const float* x     = (const float*)d_in[0];
    const float* freqs = (const float*)d_in[1];
    const float* wq    = (const float*)d_in[2];
    const float* bq    = (const float*)d_in[3];
    const float* wk    = (const float*)d_in[4];
    const float* bk    = (const float*)d_in[5];
    const float* wv    = (const float*)d_in[6];
    const float* bv    = (const float*)d_in[7];
    const float* wo    = (const float*)d_in[8];
    const float* bo    = (const float*)d_in[9];
    const float* gq    = (const float*)d_in[10];
    const float* gk    = (const float*)d_in[11];
    float* out = (float*)d_out;

    const size_t MAT  = (size_t)4096 * 2048 * 2;   // 16 MiB
    const size_t WMAT = (size_t)2048 * 2048 * 2;   // 8 MiB
    char* p = (char*)d_ws;
    bf16* xb  = (bf16*)p; p += MAT;
    bf16* wqb = (bf16*)p; p += WMAT;
    bf16* wkb = (bf16*)p; p += WMAT;
    bf16* wvb = (bf16*)p; p += WMAT;
    bf16* wob = (bf16*)p; p += WMAT;
    bf16* qb  = (bf16*)p; p += MAT;
    bf16* kb  = (bf16*)p; p += MAT;
    bf16* vb  = (bf16*)p; p += MAT;
    bf16* vt  = (bf16*)p; p += MAT;
    bf16* attn = qb;   // alias (safe: per-block exclusive row/col regions)

    cast_all<<<24576, 256, 0, stream>>>(x, wq, wk, wv, wo, xb, wqb, wkb, wvb, wob);

    gemm_bt<0><<<dim3(16, 32, 3), 256, 0, stream>>>(xb, wqb, wkb, wvb,
                                                    bq, bk, bv, qb, kb, vb);
    norm_prep<<<10240, 256, 0, stream>>>(qb, kb, gq, gk, freqs, vb, vt);
    attention<<<dim3(16, 32), 128, 0, stream>>>(qb, kb, vt, attn);
    gemm_bt<1><<<dim3(16, 32, 1), 256, 0, stream>>>(attn, wob, wob, wob,
                                                    bo, bo, bo, out, out, out);
}

// Round 5
// 392.321 us; speedup vs baseline: 1.2785x; 1.2785x over previous
//
#include <hip/hip_runtime.h>
#include <cstdint>

typedef __bf16 bf16;
typedef __bf16 bf16x8 __attribute__((ext_vector_type(8)));
typedef __bf16 bf16x4 __attribute__((ext_vector_type(4)));
typedef float f32x4 __attribute__((ext_vector_type(4)));

#define DIMN 2048
#define SEQ  2048
#define NH   16
#define HD   128

// -------- async global->LDS 16B helper (m97 pattern) --------
__device__ __forceinline__ void gld_lds16(const bf16* g, bf16* l) {
    __builtin_amdgcn_global_load_lds(
        (const __attribute__((address_space(1))) void*)g,
        (__attribute__((address_space(3))) void*)l,
        16, 0, 0);
}

// -------- all fp32->bf16 casts in ONE launch --------
__global__ __launch_bounds__(256) void cast_all(
    const float* __restrict__ x,
    const float* __restrict__ wq, const float* __restrict__ wk,
    const float* __restrict__ wv, const float* __restrict__ wo,
    bf16* __restrict__ xb,
    bf16* __restrict__ wqb, bf16* __restrict__ wkb,
    bf16* __restrict__ wvb, bf16* __restrict__ wob)
{
    int id = blockIdx.x;
    const float* src; bf16* dst; int i;
    if (id < 8192) { src = x; dst = xb; i = id * 256 + threadIdx.x; }
    else {
        id -= 8192;
        int w = id >> 12; id &= 4095;
        src = (w == 0) ? wq : (w == 1) ? wk : (w == 2) ? wv : wo;
        dst = (w == 0) ? wqb : (w == 1) ? wkb : (w == 2) ? wvb : wob;
        i = id * 256 + threadIdx.x;
    }
    float4 v = ((const float4*)src)[i];
    bf16x4 o;
    o[0] = (bf16)v.x; o[1] = (bf16)v.y; o[2] = (bf16)v.z; o[3] = (bf16)v.w;
    ((bf16x4*)dst)[i] = o;
}

// -------- GEMM: C[m][n] = sum_k A[m][k]*B[n][k] + bias[n]
// 128x128 tile, BK=64 (32 MFMA/barrier). Seg-XOR swizzled LDS, conflict-free.
// ~800 TF = m97-structure plateau; left as-is.
template<int OUT_F32>
__global__ __launch_bounds__(256) void gemm_bt(
    const bf16* __restrict__ A,
    const bf16* __restrict__ Bw0, const bf16* __restrict__ Bw1, const bf16* __restrict__ Bw2,
    const float* __restrict__ bias0, const float* __restrict__ bias1, const float* __restrict__ bias2,
    void* __restrict__ C0, void* __restrict__ C1, void* __restrict__ C2)
{
    const int K = DIMN, N = DIMN;
    const bf16* Bw = Bw0; const float* bias = bias0; void* Cout = C0;
    if (blockIdx.z == 1) { Bw = Bw1; bias = bias1; Cout = C1; }
    if (blockIdx.z == 2) { Bw = Bw2; bias = bias2; Cout = C2; }

    __shared__ __attribute__((aligned(16))) bf16 As[128 * 64];
    __shared__ __attribute__((aligned(16))) bf16 Bs[128 * 64];

    const int t    = threadIdx.x;
    const int lane = t & 63, wave = t >> 6;
    const int l15  = lane & 15, quad = lane >> 4;
    const int wm   = (wave >> 1) * 64, wn = (wave & 1) * 64;
    const long bm  = (long)blockIdx.y * 128;
    const long bn  = (long)blockIdx.x * 128;

    const bf16* agp[4]; const bf16* bgp[4]; bf16* asd[4]; bf16* bsd[4];
#pragma unroll
    for (int it = 0; it < 4; it++) {
        int fs  = it * 256 + t;
        int row = fs >> 3;
        int gs  = (fs & 7) ^ (row & 7);
        agp[it] = A  + (bm + row) * (long)K + gs * 8;
        bgp[it] = Bw + (bn + row) * (long)K + gs * 8;
        asd[it] = As + fs * 8;
        bsd[it] = Bs + fs * 8;
    }
    const int swl = l15 & 7;

    f32x4 acc[4][4] = {};

    for (int k0 = 0; k0 < K; k0 += 64) {
#pragma unroll
        for (int it = 0; it < 4; it++) {
            gld_lds16(agp[it] + k0, asd[it]);
            gld_lds16(bgp[it] + k0, bsd[it]);
        }
        __syncthreads();

#pragma unroll
        for (int ks2 = 0; ks2 < 2; ks2++) {
            const int sw = ((ks2 * 4 + quad) ^ swl) * 8;
            bf16x8 af[4], bfr[4];
#pragma unroll
            for (int i = 0; i < 4; i++)
                af[i] = *(const bf16x8*)(As + (wm + i * 16 + l15) * 64 + sw);
#pragma unroll
            for (int j = 0; j < 4; j++)
                bfr[j] = *(const bf16x8*)(Bs + (wn + j * 16 + l15) * 64 + sw);
#pragma unroll
            for (int i = 0; i < 4; i++)
#pragma unroll
                for (int j = 0; j < 4; j++)
                    acc[i][j] = __builtin_amdgcn_mfma_f32_16x16x32_bf16(af[i], bfr[j], acc[i][j], 0, 0, 0);
        }
        __syncthreads();
    }

#pragma unroll
    for (int j = 0; j < 4; j++) {
        const long col = bn + wn + j * 16 + l15;
        const float bv = bias[col];
#pragma unroll
        for (int i = 0; i < 4; i++) {
            const long row0 = bm + wm + i * 16 + quad * 4;
#pragma unroll
            for (int r = 0; r < 4; r++) {
                float v = acc[i][j][r] + bv;
                if (OUT_F32) ((float*)Cout)[(row0 + r) * N + col] = v;
                else         ((bf16*)Cout)[(row0 + r) * N + col] = (bf16)v;
            }
        }
    }
}

// -------- fused (RMSNorm+RoPE on q,k) + (V transpose) in one launch --------
__global__ __launch_bounds__(256) void norm_prep(
    bf16* __restrict__ q, bf16* __restrict__ k,
    const float* __restrict__ gq, const float* __restrict__ gk,
    const float* __restrict__ freqs,
    const bf16* __restrict__ vin, bf16* __restrict__ vt)
{
    const int id = blockIdx.x;
    const int t = threadIdx.x;
    if (id < 8192) {
        const int qk  = id >> 12;
        const int row = id & 4095;                 // b*SEQ + s
        bf16* ptr = qk ? k : q;
        const float* g = qk ? gk : gq;
        const float osc = qk ? 1.0f : 0.08838834764831845f;   // fold 1/sqrt(HD) into Q
        const int s = row & (SEQ - 1);
        const int lane = t & 63, wave = t >> 6;

        bf16* base = ptr + (long)row * DIMN + t * 8;
        bf16x8 raw = *(const bf16x8*)base;
        float v[8]; float ss = 0.f;
#pragma unroll
        for (int j = 0; j < 8; j++) { v[j] = (float)raw[j]; ss += v[j] * v[j]; }
#pragma unroll
        for (int off = 32; off; off >>= 1) ss += __shfl_xor(ss, off, 64);
        __shared__ float red[4];
        if (lane == 0) red[wave] = ss;
        __syncthreads();
        float tot = red[0] + red[1] + red[2] + red[3];
        float rn = rsqrtf(tot * (1.0f / DIMN) + 1e-6f);

        const int e0 = t * 8;
        bf16x8 o;
#pragma unroll
        for (int pp = 0; pp < 4; pp++) {
            int e = e0 + pp * 2;
            float xr = v[pp * 2]     * rn * g[e];
            float xi = v[pp * 2 + 1] * rn * g[e + 1];
            int lc = (e >> 1) & 63;
            float cr = freqs[s * 128 + lc * 2];
            float ci = freqs[s * 128 + lc * 2 + 1];
            o[pp * 2]     = (bf16)((xr * cr - xi * ci) * osc);
            o[pp * 2 + 1] = (bf16)((xr * ci + xi * cr) * osc);
        }
        *(bf16x8*)base = o;
    } else {
        const int tid = id - 8192;
        const int b = tid >> 10, rem = tid & 1023;
        const int st = rem & 31, ct = rem >> 5;
        __shared__ float tile[64][65];
        const int tx = t & 63, ty = t >> 6;
#pragma unroll
        for (int ii = 0; ii < 16; ii++) {
            int r = ii * 4 + ty;
            tile[r][tx] = (float)vin[((long)(b * SEQ + st * 64 + r)) * DIMN + ct * 64 + tx];
        }
        __syncthreads();
#pragma unroll
        for (int ii = 0; ii < 16; ii++) {
            int c = ii * 4 + ty;
            vt[((long)(b * DIMN + ct * 64 + c)) * SEQ + st * 64 + tx] = (bf16)tile[tx][c];
        }
    }
}

// -------- flash-style attention v3: 8 waves x BM=32/wave (proven v1 math, no spill),
// double-buffered K/V staging (prefetch kt+1 during compute -> barrier drain ~free),
// grid (x=bh, y=qt) so the 8 qt-blocks sharing a head's K/V land on one XCD.
// 1 block/CU (LDS 103 KB), 8 waves/CU.
__global__ __launch_bounds__(512, 2) void attention(
    const bf16* __restrict__ Q, const bf16* __restrict__ Kb,
    const bf16* __restrict__ Vt, bf16* __restrict__ O)
{
    __shared__ __attribute__((aligned(16))) bf16 Ksh[2][64 * 128];   // [kr][d], seg^=(kr&15)
    __shared__ __attribute__((aligned(16))) bf16 Vsh[2][128 * 64];   // [d][kr], seg^=(d&7)
    __shared__ __attribute__((aligned(16))) bf16 Psh[8][32 * 72];    // per-wave P[m][kr]
    __shared__ float Lsh[8][32];

    const int t = threadIdx.x;
    const int lane = t & 63, w = t >> 6;
    const int l15 = lane & 15, quad = lane >> 4;
    const int bh = blockIdx.x, b = bh >> 4, h = bh & 15;   // x = head: XCD-local K/V
    const int qt = blockIdx.y;
    const long qrow0 = (long)b * SEQ + qt * 256 + w * 32;
    const bf16* qbase = Q  + qrow0 * DIMN + h * HD;
    const bf16* kbase = Kb + (long)b * SEQ * DIMN + h * HD;
    const bf16* vbase = Vt + (long)bh * HD * SEQ;

    // Q fragments resident (pre-scaled by norm_prep): B[m=l15][k=quad*8+j]
    bf16x8 qf[2][4];
#pragma unroll
    for (int im = 0; im < 2; im++)
#pragma unroll
        for (int kd = 0; kd < 4; kd++)
            qf[im][kd] = *(const bf16x8*)(qbase + (long)(im * 16 + l15) * DIMN + kd * 32 + quad * 8);

    // staging offsets: 2 passes x 512 threads cover K(64 rows x 16 segs) and V(128 x 8)
    long koff[2], voff[2];
#pragma unroll
    for (int it = 0; it < 2; it++) {
        int fs = it * 512 + t;
        int kr = fs >> 4, kp = fs & 15;
        koff[it] = (long)kr * DIMN + (kp ^ (kr & 15)) * 8;
        int dr = fs >> 3, vp = fs & 7;
        voff[it] = (long)dr * SEQ + (vp ^ (dr & 7)) * 8;
    }

    f32x4 o_acc[2][8] = {};
    float Lt[2] = {0.f, 0.f};

    // prefetch kt=0 into buffer 0
#pragma unroll
    for (int it = 0; it < 2; it++) {
        gld_lds16(kbase + koff[it], &Ksh[0][(it * 512 + t) * 8]);
        gld_lds16(vbase + voff[it], &Vsh[0][(it * 512 + t) * 8]);
    }
    __syncthreads();

    for (int kt = 0; kt < 32; kt++) {
        const int cur = kt & 1;
        // prefetch next tile into the other buffer; completes under this iter's compute
        if (kt < 31) {
            const bf16* kg = kbase + (long)((kt + 1) * 64) * DIMN;
            const bf16* vg = vbase + (kt + 1) * 64;
#pragma unroll
            for (int it = 0; it < 2; it++) {
                gld_lds16(kg + koff[it], &Ksh[cur ^ 1][(it * 512 + t) * 8]);
                gld_lds16(vg + voff[it], &Vsh[cur ^ 1][(it * 512 + t) * 8]);
            }
        }
        const bf16* K0 = Ksh[cur];
        const bf16* V0 = Vsh[cur];

        // ---- S^T = K Q^T : D[kr][m] ----
        f32x4 st[4][2] = {};
#pragma unroll
        for (int jk = 0; jk < 4; jk++)
#pragma unroll
            for (int kd = 0; kd < 4; kd++) {
                bf16x8 kf = *(const bf16x8*)(K0 + (jk * 16 + l15) * 128 + (((kd * 4 + quad) ^ l15) & 15) * 8);
                st[jk][0] = __builtin_amdgcn_mfma_f32_16x16x32_bf16(kf, qf[0][kd], st[jk][0], 0, 0, 0);
                st[jk][1] = __builtin_amdgcn_mfma_f32_16x16x32_bf16(kf, qf[1][kd], st[jk][1], 0, 0, 0);
            }

        // ---- exp + P->LDS (b64) + per-lane partial L (reduction deferred) ----
#pragma unroll
        for (int im = 0; im < 2; im++) {
            float part = 0.f;
#pragma unroll
            for (int jk = 0; jk < 4; jk++) {
                bf16x4 pk;
#pragma unroll
                for (int r = 0; r < 4; r++) {
                    float e = __expf(st[jk][im][r]);
                    part += e;
                    pk[r] = (bf16)e;
                }
                *(bf16x4*)(Psh[w] + (im * 16 + l15) * 72 + jk * 16 + quad * 4) = pk;
            }
            Lt[im] += part;
        }
        // no barrier: Psh[w] wave-private, LDS in-order per wave

        // ---- O += P V ----
#pragma unroll
        for (int kd2 = 0; kd2 < 2; kd2++) {
            bf16x8 pa[2];
            pa[0] = *(const bf16x8*)(Psh[w] + (l15)      * 72 + kd2 * 32 + quad * 8);
            pa[1] = *(const bf16x8*)(Psh[w] + (16 + l15) * 72 + kd2 * 32 + quad * 8);
#pragma unroll
            for (int dj = 0; dj < 8; dj++) {
                bf16x8 vfr = *(const bf16x8*)(V0 + (dj * 16 + l15) * 64 + (((kd2 * 4 + quad) ^ l15) & 7) * 8);
                o_acc[0][dj] = __builtin_amdgcn_mfma_f32_16x16x32_bf16(pa[0], vfr, o_acc[0][dj], 0, 0, 0);
                o_acc[1][dj] = __builtin_amdgcn_mfma_f32_16x16x32_bf16(pa[1], vfr, o_acc[1][dj], 0, 0, 0);
            }
        }
        __syncthreads();   // drains this iter's prefetch (overlapped) + releases cur buffer
    }

    // deferred L reduction over quads (butterfly: all lanes hold total for m=l15)
#pragma unroll
    for (int im = 0; im < 2; im++) {
        Lt[im] += __shfl_xor(Lt[im], 16, 64);
        Lt[im] += __shfl_xor(Lt[im], 32, 64);
    }
    if (quad == 0) { Lsh[w][l15] = Lt[0]; Lsh[w][16 + l15] = Lt[1]; }
    __syncthreads();

    // normalize + write (aliases Q buffer: block (qt,bh) writes only rows/cols it alone read)
#pragma unroll
    for (int im = 0; im < 2; im++)
#pragma unroll
        for (int r = 0; r < 4; r++) {
            float inv = 1.0f / Lsh[w][im * 16 + quad * 4 + r];
            long orow = qrow0 + im * 16 + quad * 4 + r;
#pragma unroll
            for (int dj = 0; dj < 8; dj++)
                O[orow * DIMN + h * HD + dj * 16 + l15] = (bf16)(o_acc[im][dj][r] * inv);
        }
}

extern "C" void kernel_launch(void* const* d_in, const int* in_sizes, int n_in,
                              void* d_out, int out_size, void* d_ws, size_t ws_size,
                              hipStream_t stream) {
    const float* x     = (const float*)d_in[0];
    const float* freqs = (const float*)d_in[1];
    const float* wq    = (const float*)d_in[2];
    const float* bq    = (const float*)d_in[3];
    const float* wk    = (const float*)d_in[4];
    const float* bk    = (const float*)d_in[5];
    const float* wv    = (const float*)d_in[6];
    const float* bv    = (const float*)d_in[7];
    const float* wo    = (const float*)d_in[8];
    const float* bo    = (const float*)d_in[9];
    const float* gq    = (const float*)d_in[10];
    const float* gk    = (const float*)d_in[11];
    float* out = (float*)d_out;

    const size_t MAT  = (size_t)4096 * 2048 * 2;   // 16 MiB
    const size_t WMAT = (size_t)2048 * 2048 * 2;   // 8 MiB
    char* p = (char*)d_ws;
    bf16* xb  = (bf16*)p; p += MAT;
    bf16* wqb = (bf16*)p; p += WMAT;
    bf16* wkb = (bf16*)p; p += WMAT;
    bf16* wvb = (bf16*)p; p += WMAT;
    bf16* wob = (bf16*)p; p += WMAT;
    bf16* qb  = (bf16*)p; p += MAT;
    bf16* kb  = (bf16*)p; p += MAT;
    bf16* vb  = (bf16*)p; p += MAT;
    bf16* vt  = (bf16*)p; p += MAT;
    bf16* attn = qb;   // alias (safe: per-block exclusive row/col regions)

    cast_all<<<24576, 256, 0, stream>>>(x, wq, wk, wv, wo, xb, wqb, wkb, wvb, wob);

    gemm_bt<0><<<dim3(16, 32, 3), 256, 0, stream>>>(xb, wqb, wkb, wvb,
                                                    bq, bk, bv, qb, kb, vb);
    norm_prep<<<10240, 256, 0, stream>>>(qb, kb, gq, gk, freqs, vb, vt);
    attention<<<dim3(32, 8), 512, 0, stream>>>(qb, kb, vt, attn);
    gemm_bt<1><<<dim3(16, 32, 1), 256, 0, stream>>>(attn, wob, wob, wob,
                                                    bo, bo, bo, out, out, out);
}